// Round 10
// baseline (417.240 us; speedup 1.0000x reference)
//
#include <hip/hip_runtime.h>
#include <stdint.h>

#define T_SEQ 2048
#define C_DIM 2048
#define NH    16
#define HD    128
#define TT    32

typedef __attribute__((ext_vector_type(8))) short short8;
typedef __attribute__((ext_vector_type(4))) float f32x4;

#if defined(__has_builtin)
# if __has_builtin(__builtin_amdgcn_global_load_lds)
#  define HAVE_GLL 1
# endif
#endif
#ifndef HAVE_GLL
# define HAVE_GLL 0
#endif

__device__ __forceinline__ short f2bf(float f) {
    uint32_t x = __float_as_uint(f);
    uint32_t r = (x + 0x7fffu + ((x >> 16) & 1u)) >> 16;   // RNE
    return (short)r;
}
__device__ __forceinline__ float bf2f(short s) {
    return __uint_as_float(((uint32_t)(unsigned short)s) << 16);
}

// async global->LDS, 16B/lane; LDS dst is wave-uniform base, HW adds lane*16.
__device__ __forceinline__ void gload16(const short* g, short* l) {
    const int lane = threadIdx.x & 63;
#if HAVE_GLL
    __builtin_amdgcn_global_load_lds(
        (const __attribute__((address_space(1))) void*)(g + lane * 8),
        (__attribute__((address_space(3))) void*)l, 16, 0, 0);
#else
    *(short8*)(l + lane * 8) = *(const short8*)(g + lane * 8);
#endif
}

// ============ prep A-side: fp32 [M][K] -> fragment-ordered bf16 tiles ============
__global__ __launch_bounds__(256) void prep_a(
    const float* __restrict__ X, short* __restrict__ Apk, int K, int split)
{
    const int kb = blockIdx.x, mblk = blockIdx.y, tid = threadIdx.x;
    const int kpb = K / 32;
    const int nkb = kpb << split;
    const size_t hiBase = ((size_t)mblk * nkb + kb) * 4096;
    const size_t loBase = hiBase + (size_t)kpb * 4096;
#pragma unroll
    for (int itr = 0; itr < 2; ++itr) {
        const int item = itr * 256 + tid;
        const int row = item >> 2, kc = item & 3;
        const float* xp = &X[(size_t)(mblk * 128 + row) * K + kb * 32 + kc * 8];
        float4 v0 = *(const float4*)xp;
        float4 v1 = *(const float4*)(xp + 4);
        float f[8] = { v0.x, v0.y, v0.z, v0.w, v1.x, v1.y, v1.z, v1.w };
        const size_t off = (size_t)(row >> 4) * 512 + (size_t)((kc << 4) | (row & 15)) * 8;
        short h[8];
#pragma unroll
        for (int j = 0; j < 8; ++j) h[j] = f2bf(f[j]);
        int hw[4];
#pragma unroll
        for (int j = 0; j < 4; ++j) hw[j] = (h[2*j] & 0xffff) | (h[2*j+1] << 16);
        *(int4*)&Apk[hiBase + off] = make_int4(hw[0], hw[1], hw[2], hw[3]);
        if (split) {
            int lw[4];
#pragma unroll
            for (int j = 0; j < 4; ++j) {
                short a = f2bf(f[2*j]   - bf2f(h[2*j]));
                short b = f2bf(f[2*j+1] - bf2f(h[2*j+1]));
                lw[j] = (a & 0xffff) | (b << 16);
            }
            *(int4*)&Apk[loBase + off] = make_int4(lw[0], lw[1], lw[2], lw[3]);
        }
    }
}

// ============ prep B-side: fp32 [K][N] -> fragment-ordered bf16 tiles (transposed) ============
__global__ __launch_bounds__(256) void prep_b(
    const float* __restrict__ W, short* __restrict__ Bpk, int K, int N, int split)
{
    const int kb = blockIdx.x, nblk = blockIdx.y, tid = threadIdx.x;
    const int kpb = K / 32;
    const int nkb = kpb << split;
    __shared__ float Ws[32][129];
    {
        const int r = tid >> 3, cbase = (tid & 7) * 4;
#pragma unroll
        for (int itc = 0; itc < 4; ++itc) {
            const int c = cbase + itc * 32;
            const float4 v = *(const float4*)&W[(size_t)(kb * 32 + r) * N + nblk * 128 + c];
            Ws[r][c] = v.x; Ws[r][c + 1] = v.y; Ws[r][c + 2] = v.z; Ws[r][c + 3] = v.w;
        }
    }
    __syncthreads();
    const size_t hiBase = ((size_t)nblk * nkb + kb) * 4096;
    const size_t loBase = hiBase + (size_t)kpb * 4096;
#pragma unroll
    for (int itr = 0; itr < 2; ++itr) {
        const int item = itr * 256 + tid;
        const int n = item >> 2, kc = item & 3;
        float f[8];
#pragma unroll
        for (int j = 0; j < 8; ++j) f[j] = Ws[kc * 8 + j][n];
        const size_t off = (size_t)(n >> 4) * 512 + (size_t)((kc << 4) | (n & 15)) * 8;
        short h[8];
#pragma unroll
        for (int j = 0; j < 8; ++j) h[j] = f2bf(f[j]);
        int hw[4];
#pragma unroll
        for (int j = 0; j < 4; ++j) hw[j] = (h[2*j] & 0xffff) | (h[2*j+1] << 16);
        *(int4*)&Bpk[hiBase + off] = make_int4(hw[0], hw[1], hw[2], hw[3]);
        if (split) {
            int lw[4];
#pragma unroll
            for (int j = 0; j < 4; ++j) {
                short a = f2bf(f[2*j]   - bf2f(h[2*j]));
                short b = f2bf(f[2*j+1] - bf2f(h[2*j+1]));
                lw[j] = (a & 0xffff) | (b << 16);
            }
            *(int4*)&Bpk[loBase + off] = make_int4(lw[0], lw[1], lw[2], lw[3]);
        }
    }
}

#define GBAR()  __builtin_amdgcn_s_barrier()
#define LGKM0() do { asm volatile("s_waitcnt lgkmcnt(0)" ::: "memory"); \
                     __builtin_amdgcn_sched_barrier(0); } while (0)

// ============ bf16 MFMA GEMM: m201-style phase schedule, ring-2, burst prefetch ============
// BM=256, BN=128*BNP, BK=64/iter, 8 waves (BNP=2: 2x4, wave tile 128x64; BNP=1: 4x2, 64x64).
// Per iter (BNP=2), 4 phases of {ds_read subtile -> [stage t+1 in ph0] -> barrier ->
// lgkmcnt(0) -> setprio(1) 16 MFMA setprio(0) -> barrier}; B-frags held in regs across phases;
// ONE vmcnt(0) at phase-3 end (covered: t+1's loads issued in phase 0, ~3 phases earlier).
// Race: buf[(t+1)&1]'s readers all retired before iter t's first barrier (their reads are
// lgkm-gated before their final MFMAs of iter t-1); DMA lands before the phase-3 publish.
// mode: 0 = plain bf16; 2 = 2-term split (Ahi@[Bhi|Blo], A hi-only, nsteps=64).
template<int BNP>
__global__ __launch_bounds__(512, 2) void gemm_bf16_256(
    const short* __restrict__ Apk, const short* __restrict__ Bpk,
    float* __restrict__ C, int N, int gy, int nkbA, int nkbB, int nsteps, int mode)
{
    constexpr int NT2   = (2 + BNP) * 2;      // 8KB tiles per step: A 4, B 2*BNP
    constexpr int STEPB = NT2 * 8192;         // 64KB (BNP=2) / 48KB (BNP=1)
    constexpr int MR    = 4 * BNP;
    constexpr int WC    = 2 * BNP;
    __shared__ __align__(16) char smem[2 * STEPB];   // 128 KB / 96 KB

    const int tid = threadIdx.x;
    const int lane = tid & 63, w = tid >> 6;
    const int r16 = lane & 15;
    const int wr = w / WC, wc = w % WC;

    // bijective XCD swizzle (nwg % 8 == 0)
    const int nwg = gridDim.x, cpx = nwg >> 3, bid = blockIdx.x;
    const int swz = (bid & 7) * cpx + (bid >> 3);
    const int by = swz % gy, bx = swz / gy;
    const int bm = by * 256, bn = bx * (BNP * 128);
    const size_t Abase = (size_t)(2 * by) * nkbA * 4096;
    const size_t Bbase = (size_t)(BNP * bx) * nkbB * 4096;

    f32x4 acc[MR][4];
#pragma unroll
    for (int m = 0; m < MR; ++m)
#pragma unroll
        for (int n = 0; n < 4; ++n) acc[m][n] = (f32x4){0.f, 0.f, 0.f, 0.f};

    auto stage = [&](int t) {
        const int bi = t & 1;
#pragma unroll
        for (int i = 0; i < NT2; ++i) {
            const int o = (w * NT2 + i) * 1024;
            const int tileIdx = o >> 13;
            const int inTile = (o & 8191) >> 1;
            const int h = tileIdx & 1;
            const int v = 2 * t + h;
            const short* g;
            if (tileIdx < 4) {
                const int akb = (mode == 2) ? (v & 63) : v;
                g = Apk + Abase + ((size_t)(tileIdx >> 1) * nkbA + akb) * 4096 + inTile;
            } else {
                g = Bpk + Bbase + ((size_t)((tileIdx - 4) >> 1) * nkbB + v) * 4096 + inTile;
            }
            gload16(g, (short*)(smem + bi * STEPB + o));
        }
    };

    // fragment readers (fragment-ordered layout: lane-linear, conflict-free)
    auto rdA = [&](const char* buf, int fm, int kh) -> short8 {
        return *(const short8*)(buf + ((fm >> 3) * 2 + kh) * 8192 + (fm & 7) * 1024 + lane * 16);
    };
    auto rdB = [&](const char* buf, int fn, int kh) -> short8 {
        return *(const short8*)(buf + 32768 + ((fn >> 3) * 2 + kh) * 8192 + (fn & 7) * 1024 + lane * 16);
    };

    stage(0);
    asm volatile("s_waitcnt vmcnt(0)" ::: "memory");   // one uncovered drain (prologue only)
    GBAR();
    __builtin_amdgcn_sched_barrier(0);

    for (int t = 0; t < nsteps; ++t) {
        const char* buf = smem + (t & 1) * STEPB;
        short8 a[4][2], bfr[4][2];

        // ---- phase 0: read A[0..3] + B[0..1]; burst-stage t+1; MFMA quadrant (m0-3, n0-1) ----
#pragma unroll
        for (int m = 0; m < 4; ++m) {
            a[m][0] = rdA(buf, wr * MR + m, 0);
            a[m][1] = rdA(buf, wr * MR + m, 1);
        }
#pragma unroll
        for (int n = 0; n < 2; ++n) {
            bfr[n][0] = rdB(buf, wc * 4 + n, 0);
            bfr[n][1] = rdB(buf, wc * 4 + n, 1);
        }
        if (t + 1 < nsteps) stage(t + 1);
        GBAR(); LGKM0();
        __builtin_amdgcn_s_setprio(1);
#pragma unroll
        for (int m = 0; m < 4; ++m)
#pragma unroll
            for (int n = 0; n < 2; ++n) {
                acc[m][n] = __builtin_amdgcn_mfma_f32_16x16x32_bf16(a[m][0], bfr[n][0], acc[m][n], 0, 0, 0);
                acc[m][n] = __builtin_amdgcn_mfma_f32_16x16x32_bf16(a[m][1], bfr[n][1], acc[m][n], 0, 0, 0);
            }
        __builtin_amdgcn_s_setprio(0);
        GBAR();

        // ---- phase 1: read B[2..3]; MFMA quadrant (m0-3, n2-3) ----
#pragma unroll
        for (int n = 2; n < 4; ++n) {
            bfr[n][0] = rdB(buf, wc * 4 + n, 0);
            bfr[n][1] = rdB(buf, wc * 4 + n, 1);
        }
        GBAR(); LGKM0();
        __builtin_amdgcn_s_setprio(1);
#pragma unroll
        for (int m = 0; m < 4; ++m)
#pragma unroll
            for (int n = 2; n < 4; ++n) {
                acc[m][n] = __builtin_amdgcn_mfma_f32_16x16x32_bf16(a[m][0], bfr[n][0], acc[m][n], 0, 0, 0);
                acc[m][n] = __builtin_amdgcn_mfma_f32_16x16x32_bf16(a[m][1], bfr[n][1], acc[m][n], 0, 0, 0);
            }
        __builtin_amdgcn_s_setprio(0);

        if (BNP == 2) {
            GBAR();
            // ---- phase 2: read A[4..7]; MFMA quadrant (m4-7, n0-1) ----
#pragma unroll
            for (int m = 0; m < 4; ++m) {
                a[m][0] = rdA(buf, wr * MR + 4 + m, 0);
                a[m][1] = rdA(buf, wr * MR + 4 + m, 1);
            }
            GBAR(); LGKM0();
            __builtin_amdgcn_s_setprio(1);
#pragma unroll
            for (int m = 0; m < 4; ++m)
#pragma unroll
                for (int n = 0; n < 2; ++n) {
                    acc[4 + m][n] = __builtin_amdgcn_mfma_f32_16x16x32_bf16(a[m][0], bfr[n][0], acc[4 + m][n], 0, 0, 0);
                    acc[4 + m][n] = __builtin_amdgcn_mfma_f32_16x16x32_bf16(a[m][1], bfr[n][1], acc[4 + m][n], 0, 0, 0);
                }
            __builtin_amdgcn_s_setprio(0);
            GBAR();

            // ---- phase 3: MFMA quadrant (m4-7, n2-3); publish buf[t+1] ----
            __builtin_amdgcn_s_setprio(1);
#pragma unroll
            for (int m = 0; m < 4; ++m)
#pragma unroll
                for (int n = 2; n < 4; ++n) {
                    acc[4 + m][n] = __builtin_amdgcn_mfma_f32_16x16x32_bf16(a[m][0], bfr[n][0], acc[4 + m][n], 0, 0, 0);
                    acc[4 + m][n] = __builtin_amdgcn_mfma_f32_16x16x32_bf16(a[m][1], bfr[n][1], acc[4 + m][n], 0, 0, 0);
                }
            __builtin_amdgcn_s_setprio(0);
        }

        asm volatile("s_waitcnt vmcnt(0)" ::: "memory");   // covered: issued in phase 0
        GBAR();                                            // publish buf[(t+1)&1]
        __builtin_amdgcn_sched_barrier(0);
    }

    // ---- epilogue: per-wave private LDS bounce (stride 68), float4 coalesced stores ----
    float* Cs = (float*)(smem + w * 4352);
    const int rq = lane >> 4;
#pragma unroll
    for (int m = 0; m < MR; ++m) {
#pragma unroll
        for (int n = 0; n < 4; ++n)
#pragma unroll
            for (int j = 0; j < 4; ++j)
                Cs[(rq * 4 + j) * 68 + n * 16 + r16] = acc[m][n][j];
#pragma unroll
        for (int it2 = 0; it2 < 4; ++it2) {
            const int r = it2 * 4 + rq;
            const float4 v = *(const float4*)&Cs[r * 68 + r16 * 4];
            const int grow = bm + wr * (MR * 16) + m * 16 + r;
            *(float4*)&C[(size_t)grow * N + bn + wc * 64 + r16 * 4] = v;
        }
    }
}

// ===================== conv3 + rmsnorm + rope, t-tiled (TT rows/block, rolling taps) ==========
__global__ __launch_bounds__(128) void conv_norm_rope(
    const float* __restrict__ qkv,
    const float* __restrict__ wq, const float* __restrict__ wk,
    const float* __restrict__ wv, const float* __restrict__ wi,
    const float* __restrict__ qnw, const float* __restrict__ knw,
    const float* __restrict__ cosT, const float* __restrict__ sinT,
    short* __restrict__ qt, short* __restrict__ kt,
    short* __restrict__ vtt, float* __restrict__ it)
{
    const int tb = blockIdx.x, h = blockIdx.y, b = blockIdx.z;
    const int d = threadIdx.x;
    const int c = h * HD + d;
    const int t0 = tb * TT;

    __shared__ float red[2][4];
    __shared__ short vt_s[128][36];

    float w0[4], w1[4], w2[4];
    {
        const float* Wt[4] = { wq, wk, wv, wi };
#pragma unroll
        for (int s = 0; s < 4; ++s) {
            const float* wp = Wt[s] + c * 3;
            w0[s] = wp[0]; w1[s] = wp[1]; w2[s] = wp[2];
        }
    }
    const float qw = qnw[d], kw = knw[d];

    float xm1[4], xm2[4];
#pragma unroll
    for (int s = 0; s < 4; ++s) {
        xm1[s] = (t0 >= 1) ? qkv[((size_t)(b * T_SEQ + t0 - 1)) * (4 * C_DIM) + s * C_DIM + c] : 0.f;
        xm2[s] = (t0 >= 2) ? qkv[((size_t)(b * T_SEQ + t0 - 2)) * (4 * C_DIM) + s * C_DIM + c] : 0.f;
    }

    const int wid = d >> 6, lane = d & 63;

    for (int tt = 0; tt < TT; ++tt) {
        const int t = t0 + tt;
        const size_t rowbase = ((size_t)(b * T_SEQ + t)) * (4 * C_DIM);
        float x0[4], z[4];
#pragma unroll
        for (int s = 0; s < 4; ++s) x0[s] = qkv[rowbase + s * C_DIM + c];
#pragma unroll
        for (int s = 0; s < 4; ++s) {
            z[s] = fmaf(w0[s], xm2[s], fmaf(w1[s], xm1[s], w2[s] * x0[s]));
            xm2[s] = xm1[s]; xm1[s] = x0[s];
        }

        float sq = z[0] * z[0], sk = z[1] * z[1];
#pragma unroll
        for (int off = 32; off > 0; off >>= 1) {
            sq += __shfl_down(sq, off);
            sk += __shfl_down(sk, off);
        }
        const int pb = tt & 1;
        if (lane == 0) { red[pb][wid * 2 + 0] = sq; red[pb][wid * 2 + 1] = sk; }
        __syncthreads();
        const float rq = rsqrtf((red[pb][0] + red[pb][2]) * (1.f / HD) + 1e-5f);
        const float rk = rsqrtf((red[pb][1] + red[pb][3]) * (1.f / HD) + 1e-5f);

        float zq = z[0] * rq * qw;
        float zk = z[1] * rk * kw;
        float pq = __shfl_xor(zq, 1);
        float pk = __shfl_xor(zk, 1);
        const float cv = cosT[t * (HD / 2) + (d >> 1)];
        const float sv = sinT[t * (HD / 2) + (d >> 1)];
        float oq = (d & 1) ? (pq * sv + zq * cv) : (zq * cv - pq * sv);
        float ok = (d & 1) ? (pk * sv + zk * cv) : (zk * cv - pk * sv);
        oq *= 0.08838834764831845f;

        const size_t o = ((size_t)(b * NH + h) * T_SEQ + t) * HD + d;
        qt[o] = f2bf(oq);
        kt[o] = f2bf(ok);
        it[o] = z[3];
        vt_s[d][tt] = f2bf(z[2]);
    }
    __syncthreads();

    short vrow[TT];
#pragma unroll
    for (int i = 0; i < TT / 4; ++i)
        *(int2*)&vrow[i * 4] = *(const int2*)&vt_s[d][i * 4];
    short* dst = &vtt[((size_t)(b * NH + h) * HD + d) * T_SEQ + t0];
#pragma unroll
    for (int i = 0; i < TT / 8; ++i)
        *(short8*)(dst + i * 8) = *(const short8*)&vrow[i * 8];
}

// ===================== bf16 MFMA causal flash attention + sigmoid gate =====================
__global__ __launch_bounds__(256, 3) void flash_mfma(
    const short* __restrict__ qt, const short* __restrict__ kt,
    const short* __restrict__ vtt, const float* __restrict__ it,
    float* __restrict__ y)
{
    __shared__ short lds_k[8192];
    __shared__ short lds_v[8192];
    __shared__ short lds_p[4096];

    const int tid = threadIdx.x;
    const int lane = tid & 63, w = tid >> 6;
    const int r16 = lane & 15, g = lane >> 4;

    const int blk = blockIdx.x;
    const int xcd = blk & 7, idx = blk >> 3;
    const int bh = xcd * 4 + (idx & 3);
    const int qt_i = 31 - (idx >> 2);
    const int b = bh >> 4, h = bh & 15;
    const int q0 = qt_i * 64;
    const int qrow = q0 + w * 16;

    char* KsB = (char*)lds_k;
    char* VsB = (char*)lds_v;
    char* PsB = (char*)lds_p + w * 2048;

    short8 qf[4];
    {
        const short* qp = qt + ((size_t)bh * T_SEQ + qrow + r16) * HD;
#pragma unroll
        for (int kc = 0; kc < 4; ++kc)
            qf[kc] = *(const short8*)(qp + kc * 32 + g * 8);
    }

    f32x4 o[8];
    float m[4], l[4];
#pragma unroll
    for (int dn = 0; dn < 8; ++dn) o[dn] = (f32x4){0.f, 0.f, 0.f, 0.f};
#pragma unroll
    for (int j = 0; j < 4; ++j) { m[j] = -1e30f; l[j] = 0.f; }

    const short* kbh = kt + (size_t)bh * T_SEQ * HD;
    const short* vbh = vtt + (size_t)bh * HD * T_SEQ;

    const int krow = tid >> 4,  kdch = tid & 15;
    const int vdr  = tid >> 3,  vkch = tid & 7;

    short8 kreg[4], vreg[4];
#pragma unroll
    for (int i = 0; i < 4; ++i) {
        kreg[i] = *(const short8*)(kbh + (size_t)(krow + i * 16) * HD + kdch * 8);
        vreg[i] = *(const short8*)(vbh + (size_t)(vdr + i * 32) * T_SEQ + vkch * 8);
    }

    for (int kti = 0; kti <= qt_i; ++kti) {
        __syncthreads();
#pragma unroll
        for (int i = 0; i < 4; ++i) {
            const int row = krow + i * 16;
            *(short8*)(KsB + row * 256 + ((kdch * 16) ^ ((row & 7) << 4))) = kreg[i];
            const int dr = vdr + i * 32;
            *(short8*)(VsB + dr * 128 + ((vkch * 16) ^ ((dr & 7) << 4))) = vreg[i];
        }
        if (kti < qt_i) {
            const int k1 = (kti + 1) * 64;
#pragma unroll
            for (int i = 0; i < 4; ++i) {
                kreg[i] = *(const short8*)(kbh + (size_t)(k1 + krow + i * 16) * HD + kdch * 8);
                vreg[i] = *(const short8*)(vbh + (size_t)(vdr + i * 32) * T_SEQ + k1 + vkch * 8);
            }
        }
        __syncthreads();

        const int k0 = kti * 64;
        f32x4 sacc[4];
#pragma unroll
        for (int nt = 0; nt < 4; ++nt) sacc[nt] = (f32x4){0.f, 0.f, 0.f, 0.f};
        __builtin_amdgcn_s_setprio(1);
#pragma unroll
        for (int nt = 0; nt < 4; ++nt) {
            const int key = nt * 16 + r16;
#pragma unroll
            for (int kc = 0; kc < 4; ++kc) {
                const short8 kf = *(const short8*)(KsB + key * 256 +
                                    ((kc * 64 + g * 16) ^ ((r16 & 7) << 4)));
                sacc[nt] = __builtin_amdgcn_mfma_f32_16x16x32_bf16(qf[kc], kf, sacc[nt], 0, 0, 0);
            }
        }
        __builtin_amdgcn_s_setprio(0);

        const bool diag = (kti == qt_i);
#pragma unroll
        for (int j = 0; j < 4; ++j) {
            const int qi = qrow + g * 4 + j;
            float s0 = sacc[0][j], s1 = sacc[1][j], s2 = sacc[2][j], s3 = sacc[3][j];
            if (diag) {
                if (k0 +      r16 > qi) s0 = -1e30f;
                if (k0 + 16 + r16 > qi) s1 = -1e30f;
                if (k0 + 32 + r16 > qi) s2 = -1e30f;
                if (k0 + 48 + r16 > qi) s3 = -1e30f;
            }
            float mx = fmaxf(fmaxf(s0, s1), fmaxf(s2, s3));
            mx = fmaxf(mx, __shfl_xor(mx, 1));
            mx = fmaxf(mx, __shfl_xor(mx, 2));
            mx = fmaxf(mx, __shfl_xor(mx, 4));
            mx = fmaxf(mx, __shfl_xor(mx, 8));
            if (!__all(mx <= m[j] + 8.f)) {
                const float mn = fmaxf(m[j], mx);
                const float corr = __expf(m[j] - mn);
                m[j] = mn;
                l[j] *= corr;
#pragma unroll
                for (int dn = 0; dn < 8; ++dn) o[dn][j] *= corr;
            }
            float p0 = __expf(s0 - m[j]), p1 = __expf(s1 - m[j]);
            float p2 = __expf(s2 - m[j]), p3 = __expf(s3 - m[j]);
            float ps = p0 + p1 + p2 + p3;
            ps += __shfl_xor(ps, 1);
            ps += __shfl_xor(ps, 2);
            ps += __shfl_xor(ps, 4);
            ps += __shfl_xor(ps, 8);
            l[j] += ps;
            const int row = g * 4 + j;
            const int rsw = (row & 7) << 4;
            *(short*)(PsB + row * 128 + ((0  + r16 * 2) ^ rsw)) = f2bf(p0);
            *(short*)(PsB + row * 128 + ((32 + r16 * 2) ^ rsw)) = f2bf(p1);
            *(short*)(PsB + row * 128 + ((64 + r16 * 2) ^ rsw)) = f2bf(p2);
            *(short*)(PsB + row * 128 + ((96 + r16 * 2) ^ rsw)) = f2bf(p3);
        }

        short8 pf[2];
#pragma unroll
        for (int kc2 = 0; kc2 < 2; ++kc2)
            pf[kc2] = *(const short8*)(PsB + r16 * 128 +
                        ((kc2 * 64 + g * 16) ^ ((r16 & 7) << 4)));
        __builtin_amdgcn_s_setprio(1);
#pragma unroll
        for (int dn = 0; dn < 8; ++dn) {
            const int d = dn * 16 + r16;
#pragma unroll
            for (int kc2 = 0; kc2 < 2; ++kc2) {
                const short8 vf = *(const short8*)(VsB + d * 128 +
                                    ((kc2 * 64 + g * 16) ^ ((r16 & 7) << 4)));
                o[dn] = __builtin_amdgcn_mfma_f32_16x16x32_bf16(pf[kc2], vf, o[dn], 0, 0, 0);
            }
        }
        __builtin_amdgcn_s_setprio(0);
    }

#pragma unroll
    for (int j = 0; j < 4; ++j) {
        const float inv = 1.f / l[j];
        const int t = qrow + g * 4 + j;
        const float* ip = it + ((size_t)bh * T_SEQ + t) * HD;
        float* yp = y + ((size_t)(b * T_SEQ + t)) * C_DIM + h * HD;
#pragma unroll
        for (int dn = 0; dn < 8; ++dn) {
            const int d = dn * 16 + r16;
            const float gate = 1.f / (1.f + __expf(-ip[d]));
            yp[d] = o[dn][j] * inv * gate;
        }
    }
}

// ===================== launch =====================
extern "C" void kernel_launch(void* const* d_in, const int* in_sizes, int n_in,
                              void* d_out, int out_size, void* d_ws, size_t ws_size,
                              hipStream_t stream)
{
    const float* x     = (const float*)d_in[0];
    const float* cosT  = (const float*)d_in[1];
    const float* sinT  = (const float*)d_in[2];
    const float* Wqkv  = (const float*)d_in[3];
    const float* wq    = (const float*)d_in[4];
    const float* wk    = (const float*)d_in[5];
    const float* wv    = (const float*)d_in[6];
    const float* wi    = (const float*)d_in[7];
    const float* qnw   = (const float*)d_in[8];
    const float* knw   = (const float*)d_in[9];
    const float* Wproj = (const float*)d_in[10];
    float* out = (float*)d_out;

    char* ws = (char*)d_ws;
    const size_t MiB = 1048576;
    float* qkv      = (float*)(ws);
    float* y        = (float*)(ws);
    short* y_pk     = (short*)(ws + 32 * MiB);
    short* Wproj_pk = (short*)(ws + 64 * MiB);
    short* qt  = (short*)(ws + 128 * MiB);
    short* ktp = (short*)(ws + 144 * MiB);
    short* vtt = (short*)(ws + 160 * MiB);
    float* itp = (float*)(ws + 176 * MiB);
    short* x_pk     = (short*)(ws + 128 * MiB);
    short* Wqkv_pk  = (short*)(ws + 144 * MiB);

    // ---- stage A: qkv = x @ Wqkv (phase-scheduled BK=64 ring-2) ----
    prep_a<<<dim3(64, 32), 256, 0, stream>>>(x, x_pk, 2048, 0);
    prep_b<<<dim3(64, 64), 256, 0, stream>>>(Wqkv, Wqkv_pk, 2048, 8192, 0);
    gemm_bf16_256<2><<<dim3(512), 512, 0, stream>>>(x_pk, Wqkv_pk, qkv, 8192, 16, 64, 64, 32, 0);

    // ---- stage B: conv + rmsnorm + rope, t-tiled ----
    conv_norm_rope<<<dim3(T_SEQ / TT, NH, 2), 128, 0, stream>>>(
        qkv, wq, wk, wv, wi, qnw, knw, cosT, sinT, qt, ktp, vtt, itp);

    // ---- stage C: bf16 MFMA flash attention (async-stage + defer-max) ----
    flash_mfma<<<dim3(32 * 32), 256, 0, stream>>>(qt, ktp, vtt, itp, y);

    // ---- stage D: out = y @ Wproj (2-term split, phase-scheduled) ----
    prep_a<<<dim3(64, 32), 256, 0, stream>>>(y, y_pk, 2048, 0);
    prep_b<<<dim3(64, 16), 256, 0, stream>>>(Wproj, Wproj_pk, 2048, 2048, 1);
    gemm_bf16_256<1><<<dim3(256), 512, 0, stream>>>(y_pk, Wproj_pk, out, 2048, 16, 64, 128, 64, 2);
}

// Round 11
// 392.461 us; speedup vs baseline: 1.0631x; 1.0631x over previous
//
#include <hip/hip_runtime.h>
#include <stdint.h>

#define T_SEQ 2048
#define C_DIM 2048
#define NH    16
#define HD    128
#define TT    32

typedef __attribute__((ext_vector_type(8))) short short8;
typedef __attribute__((ext_vector_type(4))) float f32x4;

#if defined(__has_builtin)
# if __has_builtin(__builtin_amdgcn_global_load_lds)
#  define HAVE_GLL 1
# endif
#endif
#ifndef HAVE_GLL
# define HAVE_GLL 0
#endif

__device__ __forceinline__ short f2bf(float f) {
    uint32_t x = __float_as_uint(f);
    uint32_t r = (x + 0x7fffu + ((x >> 16) & 1u)) >> 16;   // RNE
    return (short)r;
}
__device__ __forceinline__ float bf2f(short s) {
    return __uint_as_float(((uint32_t)(unsigned short)s) << 16);
}

// async global->LDS, 16B/lane; LDS dst is wave-uniform base, HW adds lane*16.
__device__ __forceinline__ void gload16(const short* g, short* l) {
    const int lane = threadIdx.x & 63;
#if HAVE_GLL
    __builtin_amdgcn_global_load_lds(
        (const __attribute__((address_space(1))) void*)(g + lane * 8),
        (__attribute__((address_space(3))) void*)l, 16, 0, 0);
#else
    *(short8*)(l + lane * 8) = *(const short8*)(g + lane * 8);
#endif
}

// ============ prep A-side: fp32 [M][K] -> fragment-ordered bf16 tiles ============
__global__ __launch_bounds__(256) void prep_a(
    const float* __restrict__ X, short* __restrict__ Apk, int K, int split)
{
    const int kb = blockIdx.x, mblk = blockIdx.y, tid = threadIdx.x;
    const int kpb = K / 32;
    const int nkb = kpb << split;
    const size_t hiBase = ((size_t)mblk * nkb + kb) * 4096;
    const size_t loBase = hiBase + (size_t)kpb * 4096;
#pragma unroll
    for (int itr = 0; itr < 2; ++itr) {
        const int item = itr * 256 + tid;
        const int row = item >> 2, kc = item & 3;
        const float* xp = &X[(size_t)(mblk * 128 + row) * K + kb * 32 + kc * 8];
        float4 v0 = *(const float4*)xp;
        float4 v1 = *(const float4*)(xp + 4);
        float f[8] = { v0.x, v0.y, v0.z, v0.w, v1.x, v1.y, v1.z, v1.w };
        const size_t off = (size_t)(row >> 4) * 512 + (size_t)((kc << 4) | (row & 15)) * 8;
        short h[8];
#pragma unroll
        for (int j = 0; j < 8; ++j) h[j] = f2bf(f[j]);
        int hw[4];
#pragma unroll
        for (int j = 0; j < 4; ++j) hw[j] = (h[2*j] & 0xffff) | (h[2*j+1] << 16);
        *(int4*)&Apk[hiBase + off] = make_int4(hw[0], hw[1], hw[2], hw[3]);
        if (split) {
            int lw[4];
#pragma unroll
            for (int j = 0; j < 4; ++j) {
                short a = f2bf(f[2*j]   - bf2f(h[2*j]));
                short b = f2bf(f[2*j+1] - bf2f(h[2*j+1]));
                lw[j] = (a & 0xffff) | (b << 16);
            }
            *(int4*)&Apk[loBase + off] = make_int4(lw[0], lw[1], lw[2], lw[3]);
        }
    }
}

// ============ prep B-side: fp32 [K][N] -> fragment-ordered bf16 tiles (transposed) ============
__global__ __launch_bounds__(256) void prep_b(
    const float* __restrict__ W, short* __restrict__ Bpk, int K, int N, int split)
{
    const int kb = blockIdx.x, nblk = blockIdx.y, tid = threadIdx.x;
    const int kpb = K / 32;
    const int nkb = kpb << split;
    __shared__ float Ws[32][129];
    {
        const int r = tid >> 3, cbase = (tid & 7) * 4;
#pragma unroll
        for (int itc = 0; itc < 4; ++itc) {
            const int c = cbase + itc * 32;
            const float4 v = *(const float4*)&W[(size_t)(kb * 32 + r) * N + nblk * 128 + c];
            Ws[r][c] = v.x; Ws[r][c + 1] = v.y; Ws[r][c + 2] = v.z; Ws[r][c + 3] = v.w;
        }
    }
    __syncthreads();
    const size_t hiBase = ((size_t)nblk * nkb + kb) * 4096;
    const size_t loBase = hiBase + (size_t)kpb * 4096;
#pragma unroll
    for (int itr = 0; itr < 2; ++itr) {
        const int item = itr * 256 + tid;
        const int n = item >> 2, kc = item & 3;
        float f[8];
#pragma unroll
        for (int j = 0; j < 8; ++j) f[j] = Ws[kc * 8 + j][n];
        const size_t off = (size_t)(n >> 4) * 512 + (size_t)((kc << 4) | (n & 15)) * 8;
        short h[8];
#pragma unroll
        for (int j = 0; j < 8; ++j) h[j] = f2bf(f[j]);
        int hw[4];
#pragma unroll
        for (int j = 0; j < 4; ++j) hw[j] = (h[2*j] & 0xffff) | (h[2*j+1] << 16);
        *(int4*)&Bpk[hiBase + off] = make_int4(hw[0], hw[1], hw[2], hw[3]);
        if (split) {
            int lw[4];
#pragma unroll
            for (int j = 0; j < 4; ++j) {
                short a = f2bf(f[2*j]   - bf2f(h[2*j]));
                short b = f2bf(f[2*j+1] - bf2f(h[2*j+1]));
                lw[j] = (a & 0xffff) | (b << 16);
            }
            *(int4*)&Bpk[loBase + off] = make_int4(lw[0], lw[1], lw[2], lw[3]);
        }
    }
}

// ============ bf16 MFMA GEMM: round-9 schedule (BK=64, ring-2, single barrier + covered vmcnt(0)) ====
// REVERTED to round-9 exactly (phase-split regressed twice: R7 -19%, R10 -11%).
// cbf16: 0 = fp32 C, 1 = bf16 C (row-major), for qkv.
// mode: 0 = plain bf16; 2 = 2-term split (Ahi@[Bhi|Blo], A hi-only, nsteps=64).
template<int BNP>
__global__ __launch_bounds__(512, 2) void gemm_bf16_256(
    const short* __restrict__ Apk, const short* __restrict__ Bpk,
    void* __restrict__ Cv, int N, int gy, int nkbA, int nkbB, int nsteps, int mode, int cbf16)
{
    constexpr int NT2   = (2 + BNP) * 2;
    constexpr int STEPB = NT2 * 8192;
    constexpr int MR    = 4 * BNP;
    constexpr int WC    = 2 * BNP;
    __shared__ __align__(16) char smem[2 * STEPB];

    const int tid = threadIdx.x;
    const int lane = tid & 63, w = tid >> 6;
    const int r16 = lane & 15;
    const int wr = w / WC, wc = w % WC;

    const int nwg = gridDim.x, cpx = nwg >> 3, bid = blockIdx.x;
    const int swz = (bid & 7) * cpx + (bid >> 3);
    const int by = swz % gy, bx = swz / gy;
    const int bm = by * 256, bn = bx * (BNP * 128);
    const size_t Abase = (size_t)(2 * by) * nkbA * 4096;
    const size_t Bbase = (size_t)(BNP * bx) * nkbB * 4096;

    f32x4 acc[MR][4];
#pragma unroll
    for (int m = 0; m < MR; ++m)
#pragma unroll
        for (int n = 0; n < 4; ++n) acc[m][n] = (f32x4){0.f, 0.f, 0.f, 0.f};

    auto stage = [&](int t) {
        const int bi = t & 1;
#pragma unroll
        for (int i = 0; i < NT2; ++i) {
            const int o = (w * NT2 + i) * 1024;
            const int tileIdx = o >> 13;
            const int inTile = (o & 8191) >> 1;
            const int h = tileIdx & 1;
            const int v = 2 * t + h;
            const short* g;
            if (tileIdx < 4) {
                const int akb = (mode == 2) ? (v & 63) : v;
                g = Apk + Abase + ((size_t)(tileIdx >> 1) * nkbA + akb) * 4096 + inTile;
            } else {
                g = Bpk + Bbase + ((size_t)((tileIdx - 4) >> 1) * nkbB + v) * 4096 + inTile;
            }
            gload16(g, (short*)(smem + bi * STEPB + o));
        }
    };

    stage(0);
    __builtin_amdgcn_sched_barrier(0);

    for (int t = 0; t < nsteps; ++t) {
        asm volatile("s_waitcnt vmcnt(0)" ::: "memory");
        __builtin_amdgcn_s_barrier();
        __builtin_amdgcn_sched_barrier(0);
        const char* buf = smem + (t & 1) * STEPB;

#pragma unroll
        for (int h = 0; h < 2; ++h) {
            short8 af[MR], bfr[4];
#pragma unroll
            for (int n = 0; n < 4; ++n) {
                const int fn = wc * 4 + n;
                bfr[n] = *(const short8*)(buf + 32768 + ((fn >> 3) * 2 + h) * 8192
                                              + (fn & 7) * 1024 + lane * 16);
            }
#pragma unroll
            for (int m = 0; m < MR; ++m) {
                const int fm = wr * MR + m;
                af[m] = *(const short8*)(buf + ((fm >> 3) * 2 + h) * 8192
                                             + (fm & 7) * 1024 + lane * 16);
            }
            if (h == 0 && t + 1 < nsteps) stage(t + 1);

            __builtin_amdgcn_s_setprio(1);
#pragma unroll
            for (int m = 0; m < MR; ++m)
#pragma unroll
                for (int n = 0; n < 4; ++n)
                    acc[m][n] = __builtin_amdgcn_mfma_f32_16x16x32_bf16(af[m], bfr[n], acc[m][n], 0, 0, 0);
            __builtin_amdgcn_s_setprio(0);
        }
    }

    // ---- epilogue: per-wave private LDS bounce (stride 68), coalesced stores (f32 or bf16) ----
    __builtin_amdgcn_s_barrier();
    float* Cs = (float*)(smem + w * 4352);
    const int rq = lane >> 4;
#pragma unroll
    for (int m = 0; m < MR; ++m) {
#pragma unroll
        for (int n = 0; n < 4; ++n)
#pragma unroll
            for (int j = 0; j < 4; ++j)
                Cs[(rq * 4 + j) * 68 + n * 16 + r16] = acc[m][n][j];
#pragma unroll
        for (int it2 = 0; it2 < 4; ++it2) {
            const int r = it2 * 4 + rq;
            const float4 v = *(const float4*)&Cs[r * 68 + r16 * 4];
            const int grow = bm + wr * (MR * 16) + m * 16 + r;
            const int gcol = bn + wc * 64 + r16 * 4;
            if (!cbf16) {
                *(float4*)&((float*)Cv)[(size_t)grow * N + gcol] = v;
            } else {
                short s0 = f2bf(v.x), s1 = f2bf(v.y), s2 = f2bf(v.z), s3 = f2bf(v.w);
                *(int2*)&((short*)Cv)[(size_t)grow * N + gcol] =
                    make_int2((s0 & 0xffff) | (s1 << 16), (s2 & 0xffff) | (s3 << 16));
            }
        }
    }
}

// ===================== conv3 + rmsnorm + rope, t-tiled; qkv bf16 in, intent bf16 out ==========
__global__ __launch_bounds__(128) void conv_norm_rope(
    const short* __restrict__ qkv,
    const float* __restrict__ wq, const float* __restrict__ wk,
    const float* __restrict__ wv, const float* __restrict__ wi,
    const float* __restrict__ qnw, const float* __restrict__ knw,
    const float* __restrict__ cosT, const float* __restrict__ sinT,
    short* __restrict__ qt, short* __restrict__ kt,
    short* __restrict__ vtt, short* __restrict__ it)
{
    const int tb = blockIdx.x, h = blockIdx.y, b = blockIdx.z;
    const int d = threadIdx.x;
    const int c = h * HD + d;
    const int t0 = tb * TT;

    __shared__ float red[2][4];
    __shared__ short vt_s[128][36];

    float w0[4], w1[4], w2[4];
    {
        const float* Wt[4] = { wq, wk, wv, wi };
#pragma unroll
        for (int s = 0; s < 4; ++s) {
            const float* wp = Wt[s] + c * 3;
            w0[s] = wp[0]; w1[s] = wp[1]; w2[s] = wp[2];
        }
    }
    const float qw = qnw[d], kw = knw[d];

    float xm1[4], xm2[4];
#pragma unroll
    for (int s = 0; s < 4; ++s) {
        xm1[s] = (t0 >= 1) ? bf2f(qkv[((size_t)(b * T_SEQ + t0 - 1)) * (4 * C_DIM) + s * C_DIM + c]) : 0.f;
        xm2[s] = (t0 >= 2) ? bf2f(qkv[((size_t)(b * T_SEQ + t0 - 2)) * (4 * C_DIM) + s * C_DIM + c]) : 0.f;
    }

    const int wid = d >> 6, lane = d & 63;

    for (int tt = 0; tt < TT; ++tt) {
        const int t = t0 + tt;
        const size_t rowbase = ((size_t)(b * T_SEQ + t)) * (4 * C_DIM);
        float x0[4], z[4];
#pragma unroll
        for (int s = 0; s < 4; ++s) x0[s] = bf2f(qkv[rowbase + s * C_DIM + c]);
#pragma unroll
        for (int s = 0; s < 4; ++s) {
            z[s] = fmaf(w0[s], xm2[s], fmaf(w1[s], xm1[s], w2[s] * x0[s]));
            xm2[s] = xm1[s]; xm1[s] = x0[s];
        }

        float sq = z[0] * z[0], sk = z[1] * z[1];
#pragma unroll
        for (int off = 32; off > 0; off >>= 1) {
            sq += __shfl_down(sq, off);
            sk += __shfl_down(sk, off);
        }
        const int pb = tt & 1;
        if (lane == 0) { red[pb][wid * 2 + 0] = sq; red[pb][wid * 2 + 1] = sk; }
        __syncthreads();
        const float rq = rsqrtf((red[pb][0] + red[pb][2]) * (1.f / HD) + 1e-5f);
        const float rk = rsqrtf((red[pb][1] + red[pb][3]) * (1.f / HD) + 1e-5f);

        float zq = z[0] * rq * qw;
        float zk = z[1] * rk * kw;
        float pq = __shfl_xor(zq, 1);
        float pk = __shfl_xor(zk, 1);
        const float cv = cosT[t * (HD / 2) + (d >> 1)];
        const float sv = sinT[t * (HD / 2) + (d >> 1)];
        float oq = (d & 1) ? (pq * sv + zq * cv) : (zq * cv - pq * sv);
        float ok = (d & 1) ? (pk * sv + zk * cv) : (zk * cv - pk * sv);
        oq *= 0.08838834764831845f;

        const size_t o = ((size_t)(b * NH + h) * T_SEQ + t) * HD + d;
        qt[o] = f2bf(oq);
        kt[o] = f2bf(ok);
        it[o] = f2bf(z[3]);
        vt_s[d][tt] = f2bf(z[2]);
    }
    __syncthreads();

    short vrow[TT];
#pragma unroll
    for (int i = 0; i < TT / 4; ++i)
        *(int2*)&vrow[i * 4] = *(const int2*)&vt_s[d][i * 4];
    short* dst = &vtt[((size_t)(b * NH + h) * HD + d) * T_SEQ + t0];
#pragma unroll
    for (int i = 0; i < TT / 8; ++i)
        *(short8*)(dst + i * 8) = *(const short8*)&vrow[i * 8];
}

// ===================== bf16 MFMA causal flash attention + sigmoid gate =====================
// Emits y directly as fragment-ordered bf16 tiles (y_pk, nkb=64) -> stage D consumes without prep.
__global__ __launch_bounds__(256, 3) void flash_mfma(
    const short* __restrict__ qt, const short* __restrict__ kt,
    const short* __restrict__ vtt, const short* __restrict__ it,
    short* __restrict__ y_pk)
{
    __shared__ short lds_k[8192];
    __shared__ short lds_v[8192];
    __shared__ short lds_p[4096];

    const int tid = threadIdx.x;
    const int lane = tid & 63, w = tid >> 6;
    const int r16 = lane & 15, g = lane >> 4;

    const int blk = blockIdx.x;
    const int xcd = blk & 7, idx = blk >> 3;
    const int bh = xcd * 4 + (idx & 3);
    const int qt_i = 31 - (idx >> 2);
    const int b = bh >> 4, h = bh & 15;
    const int q0 = qt_i * 64;
    const int qrow = q0 + w * 16;

    char* KsB = (char*)lds_k;
    char* VsB = (char*)lds_v;
    char* PsB = (char*)lds_p + w * 2048;

    short8 qf[4];
    {
        const short* qp = qt + ((size_t)bh * T_SEQ + qrow + r16) * HD;
#pragma unroll
        for (int kc = 0; kc < 4; ++kc)
            qf[kc] = *(const short8*)(qp + kc * 32 + g * 8);
    }

    f32x4 o[8];
    float m[4], l[4];
#pragma unroll
    for (int dn = 0; dn < 8; ++dn) o[dn] = (f32x4){0.f, 0.f, 0.f, 0.f};
#pragma unroll
    for (int j = 0; j < 4; ++j) { m[j] = -1e30f; l[j] = 0.f; }

    const short* kbh = kt + (size_t)bh * T_SEQ * HD;
    const short* vbh = vtt + (size_t)bh * HD * T_SEQ;

    const int krow = tid >> 4,  kdch = tid & 15;
    const int vdr  = tid >> 3,  vkch = tid & 7;

    short8 kreg[4], vreg[4];
#pragma unroll
    for (int i = 0; i < 4; ++i) {
        kreg[i] = *(const short8*)(kbh + (size_t)(krow + i * 16) * HD + kdch * 8);
        vreg[i] = *(const short8*)(vbh + (size_t)(vdr + i * 32) * T_SEQ + vkch * 8);
    }

    for (int kti = 0; kti <= qt_i; ++kti) {
        __syncthreads();
#pragma unroll
        for (int i = 0; i < 4; ++i) {
            const int row = krow + i * 16;
            *(short8*)(KsB + row * 256 + ((kdch * 16) ^ ((row & 7) << 4))) = kreg[i];
            const int dr = vdr + i * 32;
            *(short8*)(VsB + dr * 128 + ((vkch * 16) ^ ((dr & 7) << 4))) = vreg[i];
        }
        if (kti < qt_i) {
            const int k1 = (kti + 1) * 64;
#pragma unroll
            for (int i = 0; i < 4; ++i) {
                kreg[i] = *(const short8*)(kbh + (size_t)(k1 + krow + i * 16) * HD + kdch * 8);
                vreg[i] = *(const short8*)(vbh + (size_t)(vdr + i * 32) * T_SEQ + k1 + vkch * 8);
            }
        }
        __syncthreads();

        const int k0 = kti * 64;
        f32x4 sacc[4];
#pragma unroll
        for (int nt = 0; nt < 4; ++nt) sacc[nt] = (f32x4){0.f, 0.f, 0.f, 0.f};
        __builtin_amdgcn_s_setprio(1);
#pragma unroll
        for (int nt = 0; nt < 4; ++nt) {
            const int key = nt * 16 + r16;
#pragma unroll
            for (int kc = 0; kc < 4; ++kc) {
                const short8 kf = *(const short8*)(KsB + key * 256 +
                                    ((kc * 64 + g * 16) ^ ((r16 & 7) << 4)));
                sacc[nt] = __builtin_amdgcn_mfma_f32_16x16x32_bf16(qf[kc], kf, sacc[nt], 0, 0, 0);
            }
        }
        __builtin_amdgcn_s_setprio(0);

        const bool diag = (kti == qt_i);
#pragma unroll
        for (int j = 0; j < 4; ++j) {
            const int qi = qrow + g * 4 + j;
            float s0 = sacc[0][j], s1 = sacc[1][j], s2 = sacc[2][j], s3 = sacc[3][j];
            if (diag) {
                if (k0 +      r16 > qi) s0 = -1e30f;
                if (k0 + 16 + r16 > qi) s1 = -1e30f;
                if (k0 + 32 + r16 > qi) s2 = -1e30f;
                if (k0 + 48 + r16 > qi) s3 = -1e30f;
            }
            float mx = fmaxf(fmaxf(s0, s1), fmaxf(s2, s3));
            mx = fmaxf(mx, __shfl_xor(mx, 1));
            mx = fmaxf(mx, __shfl_xor(mx, 2));
            mx = fmaxf(mx, __shfl_xor(mx, 4));
            mx = fmaxf(mx, __shfl_xor(mx, 8));
            if (!__all(mx <= m[j] + 8.f)) {
                const float mn = fmaxf(m[j], mx);
                const float corr = __expf(m[j] - mn);
                m[j] = mn;
                l[j] *= corr;
#pragma unroll
                for (int dn = 0; dn < 8; ++dn) o[dn][j] *= corr;
            }
            float p0 = __expf(s0 - m[j]), p1 = __expf(s1 - m[j]);
            float p2 = __expf(s2 - m[j]), p3 = __expf(s3 - m[j]);
            float ps = p0 + p1 + p2 + p3;
            ps += __shfl_xor(ps, 1);
            ps += __shfl_xor(ps, 2);
            ps += __shfl_xor(ps, 4);
            ps += __shfl_xor(ps, 8);
            l[j] += ps;
            const int row = g * 4 + j;
            const int rsw = (row & 7) << 4;
            *(short*)(PsB + row * 128 + ((0  + r16 * 2) ^ rsw)) = f2bf(p0);
            *(short*)(PsB + row * 128 + ((32 + r16 * 2) ^ rsw)) = f2bf(p1);
            *(short*)(PsB + row * 128 + ((64 + r16 * 2) ^ rsw)) = f2bf(p2);
            *(short*)(PsB + row * 128 + ((96 + r16 * 2) ^ rsw)) = f2bf(p3);
        }

        short8 pf[2];
#pragma unroll
        for (int kc2 = 0; kc2 < 2; ++kc2)
            pf[kc2] = *(const short8*)(PsB + r16 * 128 +
                        ((kc2 * 64 + g * 16) ^ ((r16 & 7) << 4)));
        __builtin_amdgcn_s_setprio(1);
#pragma unroll
        for (int dn = 0; dn < 8; ++dn) {
            const int d = dn * 16 + r16;
#pragma unroll
            for (int kc2 = 0; kc2 < 2; ++kc2) {
                const short8 vf = *(const short8*)(VsB + d * 128 +
                                    ((kc2 * 64 + g * 16) ^ ((r16 & 7) << 4)));
                o[dn] = __builtin_amdgcn_mfma_f32_16x16x32_bf16(pf[kc2], vf, o[dn], 0, 0, 0);
            }
        }
        __builtin_amdgcn_s_setprio(0);
    }

    // ---- epilogue: gate, then emit fragment-ordered bf16 tiles via LDS bounce ----
    __syncthreads();                       // K/V LDS reads done; reuse lds_k as ybuf
    short* ybuf = lds_k;                   // [64 rows][128 cols] bf16
#pragma unroll
    for (int j = 0; j < 4; ++j) {
        const float inv = 1.f / l[j];
        const int t = qrow + g * 4 + j;
        const short* ip = it + ((size_t)bh * T_SEQ + t) * HD;
        const int rl = w * 16 + g * 4 + j;
#pragma unroll
        for (int dn = 0; dn < 8; ++dn) {
            const int d = dn * 16 + r16;
            const float gate = 1.f / (1.f + __expf(-bf2f(ip[d])));
            ybuf[rl * 128 + d] = f2bf(o[dn][j] * inv * gate);
        }
    }
    __syncthreads();

    // fragment-order writeout: rows r = b*T_SEQ + q0 + rl, cols c = h*128 + cl
    // y_pk tile layout (nkb=64): base=(mblk*64+kb)*4096, off=fm*512+lane'*8+j
    // lane' = ((c%32)>>3)<<4 | (r%16); consecutive tid -> consecutive lane' -> 1KB contiguous.
    const int gr0 = b * T_SEQ + q0;
    const int mblk = gr0 >> 7;
    const int fm0 = (gr0 & 127) >> 4;
#pragma unroll
    for (int it2 = 0; it2 < 4; ++it2) {
        const int slot = it2 * 256 + tid;          // 0..1023 = 4 kb x 4 fm x 64 lane'
        const int kbl = slot >> 8;                 // local kb (0..3)
        const int fml = (slot >> 6) & 3;           // local fm (0..3)
        const int lp = slot & 63;
        const int rl = fml * 16 + (lp & 15);
        const int cl = kbl * 32 + (lp >> 4) * 8;
        const short8 v = *(const short8*)&ybuf[rl * 128 + cl];
        const int kb = h * 4 + kbl;
        const int fm = fm0 + fml;
        *(short8*)&y_pk[((size_t)mblk * 64 + kb) * 4096 + fm * 512 + lp * 8] = v;
    }
}

// ===================== launch =====================
extern "C" void kernel_launch(void* const* d_in, const int* in_sizes, int n_in,
                              void* d_out, int out_size, void* d_ws, size_t ws_size,
                              hipStream_t stream)
{
    const float* x     = (const float*)d_in[0];
    const float* cosT  = (const float*)d_in[1];
    const float* sinT  = (const float*)d_in[2];
    const float* Wqkv  = (const float*)d_in[3];
    const float* wq    = (const float*)d_in[4];
    const float* wk    = (const float*)d_in[5];
    const float* wv    = (const float*)d_in[6];
    const float* wi    = (const float*)d_in[7];
    const float* qnw   = (const float*)d_in[8];
    const float* knw   = (const float*)d_in[9];
    const float* Wproj = (const float*)d_in[10];
    float* out = (float*)d_out;

    char* ws = (char*)d_ws;
    const size_t MiB = 1048576;
    short* qkv      = (short*)(ws);                 // bf16 [4096][8192] = 64 MB
    short* y_pk     = (short*)(ws + 64 * MiB);      // fragment-ordered bf16, 16 MB
    short* Wproj_pk = (short*)(ws + 96 * MiB);      // 16 MB (2-term)
    short* qt  = (short*)(ws + 128 * MiB);
    short* ktp = (short*)(ws + 144 * MiB);
    short* vtt = (short*)(ws + 160 * MiB);
    short* itp = (short*)(ws + 176 * MiB);          // bf16 now, 16 MB
    short* x_pk     = (short*)(ws + 192 * MiB);     // 16 MB
    short* Wqkv_pk  = (short*)(ws + 208 * MiB);     // 32 MB -> ends at 240 MB

    // ---- stage A: qkv(bf16) = x @ Wqkv (round-9 schedule) ----
    prep_a<<<dim3(64, 32), 256, 0, stream>>>(x, x_pk, 2048, 0);
    prep_b<<<dim3(64, 64), 256, 0, stream>>>(Wqkv, Wqkv_pk, 2048, 8192, 0);
    gemm_bf16_256<2><<<dim3(512), 512, 0, stream>>>(x_pk, Wqkv_pk, qkv, 8192, 16, 64, 64, 32, 0, 1);

    // ---- stage B: conv + rmsnorm + rope (bf16 in/out) ----
    conv_norm_rope<<<dim3(T_SEQ / TT, NH, 2), 128, 0, stream>>>(
        qkv, wq, wk, wv, wi, qnw, knw, cosT, sinT, qt, ktp, vtt, itp);

    // ---- stage C: flash attention -> y_pk (fragment-ordered bf16, prep-free) ----
    flash_mfma<<<dim3(32 * 32), 256, 0, stream>>>(qt, ktp, vtt, itp, y_pk);

    // ---- stage D: out = y @ Wproj (2-term split; consumes flash's y_pk directly) ----
    prep_b<<<dim3(64, 16), 256, 0, stream>>>(Wproj, Wproj_pk, 2048, 2048, 1);
    gemm_bf16_256<1><<<dim3(256), 512, 0, stream>>>(y_pk, Wproj_pk, out, 2048, 16, 64, 128, 64, 2, 0);
}